// Round 13
// baseline (92.660 us; speedup 1.0000x reference)
//
#include <hip/hip_runtime.h>

// STFT magnitude via bf16 MFMA GEMM.
// Round 13: f-LOOP — each block stages its sX slice ONCE and loops over a
// group of f-tiles ({0,1,2},{3,4},{5,6}), cutting staging traffic 115->49MB
// and amortizing the exposed prologue over 2-3x more compute. Per-f epilogue
// stores overlap the next f-iter (no barriers after the prologue one).
// Frozen: TT=128, 3 blocks/CU, 32x32x16 MFMA, k-tiled bt, dist-2 A / dist-1 X
// register prefetch, XCD-chunked swizzle.

#define FL   800
#define HOP  200
#define CUT  401
#define NS   8000000
#define NT   40001
#define KSTEPS 25            // 800/32

#define FT   64              // freq tile per f-iter
#define TT   128             // frame tile per block
#define NTT  313             // ceil(40001/128)
#define SLICE_SH 26624       // sX shorts: 13 sweeps * 2048 (need 26200)
#define XBN  8016000         // xb length in shorts
#define BB_OFF 16032000      // byte offset of bt in ws (= XBN*2)
#define KSTRIDE 28672        // shorts per k2-pair step: 2*896*16
#define FRAG1   14336        // shorts per single k2: 896*16
#define IMAG    7168         // shorts: 448*16 (imag fidx offset)

typedef short short8 __attribute__((ext_vector_type(8)));
typedef float float4v __attribute__((ext_vector_type(4)));
typedef float f32x16 __attribute__((ext_vector_type(16)));

#define GU32 const __attribute__((address_space(1))) unsigned int*
#define LU32 __attribute__((address_space(3))) unsigned int*

__device__ inline unsigned short f2bf(float f) {
    union { float f; unsigned u; } v; v.f = f;
    unsigned r = v.u + 0x7FFFu + ((v.u >> 16) & 1u);   // RNE
    return (unsigned short)(r >> 16);
}

// ---- prep 1: x (fp32) -> xb (bf16, reflect-padded by 400) ----
__global__ void prep_x(const float* __restrict__ x, short* __restrict__ xb) {
    const int n8 = XBN / 8;
    for (int j = blockIdx.x * blockDim.x + threadIdx.x; j < n8;
         j += gridDim.x * blockDim.x) {
        const int i = j * 8;
        const int s = i - 400;
        short8 o;
        if (s >= 0 && s + 7 < NS) {
            const float4v a = *reinterpret_cast<const float4v*>(x + s);
            const float4v b = *reinterpret_cast<const float4v*>(x + s + 4);
            o[0]=f2bf(a[0]); o[1]=f2bf(a[1]); o[2]=f2bf(a[2]); o[3]=f2bf(a[3]);
            o[4]=f2bf(b[0]); o[5]=f2bf(b[1]); o[6]=f2bf(b[2]); o[7]=f2bf(b[3]);
        } else {
            #pragma unroll
            for (int q = 0; q < 8; ++q) {
                int sq = s + q;
                if (sq < 0) sq = -sq;
                else if (sq >= NS) sq = 2 * NS - 2 - sq;
                o[q] = f2bf(x[sq]);
            }
        }
        *reinterpret_cast<short8*>(xb + i) = o;
    }
}

// ---- prep 2: basis (802x800 fp32) -> bt[k2][896][16] bf16 (k-tiled) ----
__global__ void prep_b(const float* __restrict__ basis, short* __restrict__ bt) {
    const int nch = 50 * 896 * 2;     // 89600
    for (int j = blockIdx.x * blockDim.x + threadIdx.x; j < nch;
         j += gridDim.x * blockDim.x) {
        const int k2   = j / 1792;
        const int rem  = j % 1792;
        const int fidx = rem >> 1;
        const int half = rem & 1;
        int src = -1;
        if (fidx < CUT) src = fidx;                                  // real
        else if (fidx >= 448 && fidx < 448 + CUT) src = fidx - 47;   // imag
        short8 o;
        if (src >= 0) {
            const float* p = basis + (size_t)src * 800 + k2 * 16 + half * 8;
            const float4v a = *reinterpret_cast<const float4v*>(p);
            const float4v b = *reinterpret_cast<const float4v*>(p + 4);
            o[0]=f2bf(a[0]); o[1]=f2bf(a[1]); o[2]=f2bf(a[2]); o[3]=f2bf(a[3]);
            o[4]=f2bf(b[0]); o[5]=f2bf(b[1]); o[6]=f2bf(b[2]); o[7]=f2bf(b[3]);
        } else {
            #pragma unroll
            for (int q = 0; q < 8; ++q) o[q] = 0;
        }
        *reinterpret_cast<short8*>(bt + (size_t)j * 8) = o;
    }
}

#define MF32(A, X, C) C = __builtin_amdgcn_mfma_f32_32x32x16_bf16((A), (X), (C), 0, 0, 0)

// One pipeline step. CA = A(KS) (loaded 2 steps ago), CX = X(KS) (read 1 step
// ago). NA <- A(KS+2) global->reg; NX <- X(KS+1) LDS->reg.
#define BODY(KS, CA, CX, NA, NX)                                               \
  {                                                                            \
    if ((KS) <= 22) {                                                          \
      NA[0] = *reinterpret_cast<const short8*>(par + (size_t)((KS)+2)*KSTRIDE);         \
      NA[1] = *reinterpret_cast<const short8*>(par + (size_t)((KS)+2)*KSTRIDE + FRAG1); \
      NA[2] = *reinterpret_cast<const short8*>(pai + (size_t)((KS)+2)*KSTRIDE);         \
      NA[3] = *reinterpret_cast<const short8*>(pai + (size_t)((KS)+2)*KSTRIDE + FRAG1); \
    }                                                                          \
    if ((KS) <= 23) {                                                          \
      NX[0] = *reinterpret_cast<const short8*>(&sX[xoff + 0*6400 + ((KS)+1)*32]);      \
      NX[1] = *reinterpret_cast<const short8*>(&sX[xoff + 0*6400 + ((KS)+1)*32 + 16]); \
      NX[2] = *reinterpret_cast<const short8*>(&sX[xoff + 1*6400 + ((KS)+1)*32]);      \
      NX[3] = *reinterpret_cast<const short8*>(&sX[xoff + 1*6400 + ((KS)+1)*32 + 16]); \
    }                                                                          \
    __builtin_amdgcn_s_setprio(1);                                             \
    MF32(CA[0], CX[0], acc_r[0]); MF32(CA[0], CX[2], acc_r[1]);                \
    MF32(CA[2], CX[0], acc_i[0]); MF32(CA[2], CX[2], acc_i[1]);                \
    MF32(CA[1], CX[1], acc_r[0]); MF32(CA[1], CX[3], acc_r[1]);                \
    MF32(CA[3], CX[1], acc_i[0]); MF32(CA[3], CX[3], acc_i[1]);                \
    __builtin_amdgcn_s_setprio(0);                                             \
  }

__global__ __launch_bounds__(256, 3)
void stft_mag_kernel(const short* __restrict__ xb,
                     const short* __restrict__ bt,
                     float* __restrict__ out) {
    __shared__ short sX[SLICE_SH];     // 53,248 B — 3 blocks/CU

    const int tid = threadIdx.x;

    // ---- bijective XCD-chunked swizzle over 939 weighted blocks ----
    const int nwg = NTT * 3;           // 939
    const int q = nwg >> 3, r = nwg & 7;
    const int bid = blockIdx.x;
    const int xcd = bid & 7, idx = bid >> 3;
    const int wgid = (xcd < r ? xcd * (q + 1) : r * (q + 1) + (xcd - r) * q) + idx;
    const int tb = wgid / 3;           // t-tile
    const int g  = wgid % 3;           // f-group: {0,1,2} / {3,4} / {5,6}
    const int t0 = tb * TT;
    const int fbase = (g == 0) ? 0 : (g == 1) ? 3 : 5;   // f-tile start
    const int nf    = (g == 0) ? 3 : 2;                  // f-tiles this block

    const int lane = tid & 63;
    const int wid  = tid >> 6;
    const int wm   = wid >> 1;       // 0..1 -> which 32 freqs within f-tile
    const int wn   = wid & 1;        // 0..1 -> which 64 frames
    const int l31  = lane & 31;
    const int lk   = lane >> 5;      // k-half selector

    // ---- stage sX ONCE: 13 sweeps of global_load_lds width-16, clamped ----
    {
        const int g0 = t0 * HOP + tid * 8;
        short* dst = sX + tid * 8;
        #pragma unroll
        for (int it = 0; it < 13; ++it) {
            int off = g0 + it * 2048;
            if (off > XBN - 8) off = XBN - 8;   // garbage cols masked at store
            __builtin_amdgcn_global_load_lds((GU32)(xb + off),
                                             (LU32)(dst + it * 2048), 16, 0, 0);
        }
    }

    const int xoff = (wn * 64 + l31) * 200 + lk * 8;   // + ni*6400 + ks*32 (+16)

    // sX landed -> the ONLY barrier
    asm volatile("s_waitcnt vmcnt(0)" ::: "memory");
    __builtin_amdgcn_s_barrier();
    asm volatile("" ::: "memory");

    short8 A0[4], A1[4], A2[4], XA[4], XB[4];

    // ---- f-loop: reuse sX across nf f-tiles ----
    for (int fi = 0; fi < nf; ++fi) {
        const int f0 = (fbase + fi) * FT;
        const int fb = f0 + wm * 32 + l31;
        const short* par = bt + (size_t)fb * 16 + lk * 8;   // real
        const short* pai = par + IMAG;                      // imag

        // A frags for ks=0,1
        A0[0] = *reinterpret_cast<const short8*>(par);
        A0[1] = *reinterpret_cast<const short8*>(par + FRAG1);
        A0[2] = *reinterpret_cast<const short8*>(pai);
        A0[3] = *reinterpret_cast<const short8*>(pai + FRAG1);
        A1[0] = *reinterpret_cast<const short8*>(par + KSTRIDE);
        A1[1] = *reinterpret_cast<const short8*>(par + KSTRIDE + FRAG1);
        A1[2] = *reinterpret_cast<const short8*>(pai + KSTRIDE);
        A1[3] = *reinterpret_cast<const short8*>(pai + KSTRIDE + FRAG1);

        // X frags for ks=0
        XA[0] = *reinterpret_cast<const short8*>(&sX[xoff + 0*6400]);
        XA[1] = *reinterpret_cast<const short8*>(&sX[xoff + 0*6400 + 16]);
        XA[2] = *reinterpret_cast<const short8*>(&sX[xoff + 1*6400]);
        XA[3] = *reinterpret_cast<const short8*>(&sX[xoff + 1*6400 + 16]);

        f32x16 acc_r[2] = {};
        f32x16 acc_i[2] = {};

        // ---- barrier-free pipeline: steps 0..23 (unroll 6 = lcm(3,2)) ----
        #pragma unroll
        for (int jj = 0; jj < 4; ++jj) {
            BODY(6*jj + 0, A0, XA, A2, XB);
            BODY(6*jj + 1, A1, XB, A0, XA);
            BODY(6*jj + 2, A2, XA, A1, XB);
            BODY(6*jj + 3, A0, XB, A2, XA);
            BODY(6*jj + 4, A1, XA, A0, XB);
            BODY(6*jj + 5, A2, XB, A1, XA);
        }
        BODY(24, A0, XA, A1, XB);   // consumes A0 (24%3=0), XA (24%2=0)

        // ---- epilogue for this f-tile (overlaps next f-iter's steps) ----
        #pragma unroll
        for (int ni = 0; ni < 2; ++ni) {
            const int t = t0 + wn * 64 + ni * 32 + l31;
            if (t < NT) {
                #pragma unroll
                for (int reg = 0; reg < 16; ++reg) {
                    const int row = (reg & 3) + 8 * (reg >> 2) + 4 * lk;
                    const int f = f0 + wm * 32 + row;
                    if (f < CUT) {
                        const float vr = acc_r[ni][reg];
                        const float vi = acc_i[ni][reg];
                        out[(size_t)f * NT + t] = sqrtf(vr * vr + vi * vi);
                    }
                }
            }
        }
    }
}

extern "C" void kernel_launch(void* const* d_in, const int* in_sizes, int n_in,
                              void* d_out, int out_size, void* d_ws, size_t ws_size,
                              hipStream_t stream) {
    const float* x     = (const float*)d_in[0];
    const float* basis = (const float*)d_in[1];
    float* out = (float*)d_out;

    short* xb = (short*)d_ws;
    short* bt = (short*)((char*)d_ws + BB_OFF);

    prep_x<<<2048, 256, 0, stream>>>(x, xb);
    prep_b<<<350, 256, 0, stream>>>(basis, bt);

    stft_mag_kernel<<<NTT * 3, 256, 0, stream>>>(xb, bt, out);
}

// Round 14
// 85.168 us; speedup vs baseline: 1.0880x; 1.0880x over previous
//
#include <hip/hip_runtime.h>

// STFT magnitude via bf16 MFMA GEMM.
// Round 14: round-12 main structure (best: 68.5us main) + prep_x ELIMINATED —
// each block converts its raw-fp32 x slice to bf16 sX in the prologue
// (2xb128 load + 8 RNE cvt + ds_write_b128 per sweep; reflect via rare edge
// branch). Saves the stream-serialized 48MB prep_x round-trip (~9us). x is
// L3-resident so the 7x re-read is L3-served. Main loop byte-identical to
// round 12: TT=128, 3 blocks/CU, 32x32x16 MFMA, k-tiled bt, dist-2 A /
// dist-1 X register prefetch, barrier-free, XCD-chunked swizzle.

#define FL   800
#define HOP  200
#define CUT  401
#define NS   8000000
#define NT   40001
#define KSTEPS 25            // 800/32

#define FT   64              // freq tile per block
#define TT   128             // frame tile per block
#define NTT  313             // ceil(40001/128)
#define SLICE_SH 26624       // sX shorts: 13 sweeps * 2048 (need 26200)
#define KSTRIDE 28672        // shorts per k2-pair step: 2*896*16
#define FRAG1   14336        // shorts per single k2: 896*16
#define IMAG    7168         // shorts: 448*16 (imag fidx offset)

typedef short short8 __attribute__((ext_vector_type(8)));
typedef float float4v __attribute__((ext_vector_type(4)));
typedef float f32x16 __attribute__((ext_vector_type(16)));

__device__ inline unsigned short f2bf(float f) {
    union { float f; unsigned u; } v; v.f = f;
    unsigned r = v.u + 0x7FFFu + ((v.u >> 16) & 1u);   // RNE
    return (unsigned short)(r >> 16);
}

// ---- prep: basis (802x800 fp32) -> bt[k2][896][16] bf16 (k-tiled) ----
__global__ void prep_b(const float* __restrict__ basis, short* __restrict__ bt) {
    const int nch = 50 * 896 * 2;     // 89600
    for (int j = blockIdx.x * blockDim.x + threadIdx.x; j < nch;
         j += gridDim.x * blockDim.x) {
        const int k2   = j / 1792;
        const int rem  = j % 1792;
        const int fidx = rem >> 1;
        const int half = rem & 1;
        int src = -1;
        if (fidx < CUT) src = fidx;                                  // real
        else if (fidx >= 448 && fidx < 448 + CUT) src = fidx - 47;   // imag
        short8 o;
        if (src >= 0) {
            const float* p = basis + (size_t)src * 800 + k2 * 16 + half * 8;
            const float4v a = *reinterpret_cast<const float4v*>(p);
            const float4v b = *reinterpret_cast<const float4v*>(p + 4);
            o[0]=f2bf(a[0]); o[1]=f2bf(a[1]); o[2]=f2bf(a[2]); o[3]=f2bf(a[3]);
            o[4]=f2bf(b[0]); o[5]=f2bf(b[1]); o[6]=f2bf(b[2]); o[7]=f2bf(b[3]);
        } else {
            #pragma unroll
            for (int q = 0; q < 8; ++q) o[q] = 0;
        }
        *reinterpret_cast<short8*>(bt + (size_t)j * 8) = o;
    }
}

#define MF32(A, X, C) C = __builtin_amdgcn_mfma_f32_32x32x16_bf16((A), (X), (C), 0, 0, 0)

// One pipeline step. CA = A(KS) (loaded 2 steps ago), CX = X(KS) (read 1 step
// ago). NA <- A(KS+2) global->reg; NX <- X(KS+1) LDS->reg.
#define BODY(KS, CA, CX, NA, NX)                                               \
  {                                                                            \
    if ((KS) <= 22) {                                                          \
      NA[0] = *reinterpret_cast<const short8*>(par + (size_t)((KS)+2)*KSTRIDE);         \
      NA[1] = *reinterpret_cast<const short8*>(par + (size_t)((KS)+2)*KSTRIDE + FRAG1); \
      NA[2] = *reinterpret_cast<const short8*>(pai + (size_t)((KS)+2)*KSTRIDE);         \
      NA[3] = *reinterpret_cast<const short8*>(pai + (size_t)((KS)+2)*KSTRIDE + FRAG1); \
    }                                                                          \
    if ((KS) <= 23) {                                                          \
      NX[0] = *reinterpret_cast<const short8*>(&sX[xoff + 0*6400 + ((KS)+1)*32]);      \
      NX[1] = *reinterpret_cast<const short8*>(&sX[xoff + 0*6400 + ((KS)+1)*32 + 16]); \
      NX[2] = *reinterpret_cast<const short8*>(&sX[xoff + 1*6400 + ((KS)+1)*32]);      \
      NX[3] = *reinterpret_cast<const short8*>(&sX[xoff + 1*6400 + ((KS)+1)*32 + 16]); \
    }                                                                          \
    __builtin_amdgcn_s_setprio(1);                                             \
    MF32(CA[0], CX[0], acc_r[0]); MF32(CA[0], CX[2], acc_r[1]);                \
    MF32(CA[2], CX[0], acc_i[0]); MF32(CA[2], CX[2], acc_i[1]);                \
    MF32(CA[1], CX[1], acc_r[0]); MF32(CA[1], CX[3], acc_r[1]);                \
    MF32(CA[3], CX[1], acc_i[0]); MF32(CA[3], CX[3], acc_i[1]);                \
    __builtin_amdgcn_s_setprio(0);                                             \
  }

__global__ __launch_bounds__(256, 3)
void stft_mag_kernel(const float* __restrict__ x,
                     const short* __restrict__ bt,
                     float* __restrict__ out) {
    __shared__ short sX[SLICE_SH];     // 53,248 B — 3 blocks/CU

    const int tid = threadIdx.x;

    // ---- bijective XCD-chunked swizzle (nwg=2191), f-fastest ----
    const int nwg = NTT * 7;
    const int q = nwg >> 3, r = nwg & 7;
    const int bid = blockIdx.x;
    const int xcd = bid & 7, idx = bid >> 3;
    const int wgid = (xcd < r ? xcd * (q + 1) : r * (q + 1) + (xcd - r) * q) + idx;
    const int t0 = (wgid / 7) * TT;
    const int f0 = (wgid % 7) * FT;

    const int lane = tid & 63;
    const int wid  = tid >> 6;
    const int wm   = wid >> 1;       // 0..1 -> which 32 freqs
    const int wn   = wid & 1;        // 0..1 -> which 64 frames
    const int l31  = lane & 31;
    const int lk   = lane >> 5;      // k-half selector

    // ---- A-fragment base pointers into bt[k2][896][16] ----
    const int fb = f0 + wm * 32 + l31;
    const short* par = bt + (size_t)fb * 16 + lk * 8;          // real
    const short* pai = par + IMAG;                             // imag

    short8 A0[4], A1[4], A2[4], XA[4], XB[4];

    // A frags for ks=0,1 issued FIRST so they overlap the sX conversion
    A0[0] = *reinterpret_cast<const short8*>(par);
    A0[1] = *reinterpret_cast<const short8*>(par + FRAG1);
    A0[2] = *reinterpret_cast<const short8*>(pai);
    A0[3] = *reinterpret_cast<const short8*>(pai + FRAG1);
    A1[0] = *reinterpret_cast<const short8*>(par + KSTRIDE);
    A1[1] = *reinterpret_cast<const short8*>(par + KSTRIDE + FRAG1);
    A1[2] = *reinterpret_cast<const short8*>(pai + KSTRIDE);
    A1[3] = *reinterpret_cast<const short8*>(pai + KSTRIDE + FRAG1);

    // ---- prologue: convert raw fp32 x slice -> bf16 sX (reflect at edges) ----
    {
        const int base = t0 * HOP - 400;       // sample index of sX[0]
        #pragma unroll
        for (int it = 0; it < 13; ++it) {
            const int p = tid * 8 + it * 2048; // sX position
            const int s = base + p;
            short8 o;
            if (s >= 0 && s + 7 < NS) {
                const float4v a = *reinterpret_cast<const float4v*>(x + s);
                const float4v b = *reinterpret_cast<const float4v*>(x + s + 4);
                o[0]=f2bf(a[0]); o[1]=f2bf(a[1]); o[2]=f2bf(a[2]); o[3]=f2bf(a[3]);
                o[4]=f2bf(b[0]); o[5]=f2bf(b[1]); o[6]=f2bf(b[2]); o[7]=f2bf(b[3]);
            } else {
                #pragma unroll
                for (int qq = 0; qq < 8; ++qq) {
                    int sq = s + qq;
                    if (sq < 0) sq = -sq;                    // left reflect
                    else if (sq >= NS) sq = 2 * NS - 2 - sq; // right reflect
                    o[qq] = f2bf(x[sq]);
                }
            }
            *reinterpret_cast<short8*>(&sX[p]) = o;
        }
    }

    const int xoff = (wn * 64 + l31) * 200 + lk * 8;   // + ni*6400 + ks*32 (+16)

    f32x16 acc_r[2] = {};
    f32x16 acc_i[2] = {};

    // sX written by all waves -> the ONLY barrier (waits lgkm+vm)
    __syncthreads();

    // X frags for ks=0
    XA[0] = *reinterpret_cast<const short8*>(&sX[xoff + 0*6400]);
    XA[1] = *reinterpret_cast<const short8*>(&sX[xoff + 0*6400 + 16]);
    XA[2] = *reinterpret_cast<const short8*>(&sX[xoff + 1*6400]);
    XA[3] = *reinterpret_cast<const short8*>(&sX[xoff + 1*6400 + 16]);

    // ---- barrier-free main pipeline: steps 0..23 (unroll 6 = lcm(3,2)) ----
    #pragma unroll
    for (int jj = 0; jj < 4; ++jj) {
        BODY(6*jj + 0, A0, XA, A2, XB);
        BODY(6*jj + 1, A1, XB, A0, XA);
        BODY(6*jj + 2, A2, XA, A1, XB);
        BODY(6*jj + 3, A0, XB, A2, XA);
        BODY(6*jj + 4, A1, XA, A0, XB);
        BODY(6*jj + 5, A2, XB, A1, XA);
    }
    // step 24: consumes A0 (24%3=0), XA (24%2=0); no prefetch (KS>23)
    BODY(24, A0, XA, A1, XB);

    // ---- epilogue: magnitude + coalesced stores (32 lanes = 32 consecutive t) ----
    #pragma unroll
    for (int ni = 0; ni < 2; ++ni) {
        const int t = t0 + wn * 64 + ni * 32 + l31;
        if (t < NT) {
            #pragma unroll
            for (int reg = 0; reg < 16; ++reg) {
                const int row = (reg & 3) + 8 * (reg >> 2) + 4 * lk;
                const int f = f0 + wm * 32 + row;
                if (f < CUT) {
                    const float vr = acc_r[ni][reg];
                    const float vi = acc_i[ni][reg];
                    out[(size_t)f * NT + t] = sqrtf(vr * vr + vi * vi);
                }
            }
        }
    }
}

extern "C" void kernel_launch(void* const* d_in, const int* in_sizes, int n_in,
                              void* d_out, int out_size, void* d_ws, size_t ws_size,
                              hipStream_t stream) {
    const float* x     = (const float*)d_in[0];
    const float* basis = (const float*)d_in[1];
    float* out = (float*)d_out;

    short* bt = (short*)d_ws;

    prep_b<<<350, 256, 0, stream>>>(basis, bt);

    stft_mag_kernel<<<NTT * 7, 256, 0, stream>>>(x, bt, out);
}

// Round 15
// 78.196 us; speedup vs baseline: 1.1850x; 1.0892x over previous
//
#include <hip/hip_runtime.h>

// STFT magnitude via bf16 MFMA GEMM.
// Round 15: revert to round-12 main structure (best verified: 68.5us main).
// Changes vs round 12: (1) prep_b fused into prep_x (one launch; tiny basis
// work overlaps the BW-bound x conversion); (2) s_setprio removed from the
// main loop (barrier-free structure is not phase-split -> T5 gate predicts
// setprio neutral-to-harmful; only never-ablated knob).
// Frozen: TT=128, 3 blocks/CU, 32x32x16 MFMA, k-tiled bt, dist-2 A / dist-1 X
// register prefetch, barrier-free main loop, XCD-chunked swizzle.

#define FL   800
#define HOP  200
#define CUT  401
#define NS   8000000
#define NT   40001
#define KSTEPS 25            // 800/32

#define FT   64              // freq tile per block
#define TT   128             // frame tile per block
#define NTT  313             // ceil(40001/128)
#define SLICE_SH 26624       // sX shorts: 13 sweeps * 2048 (need 26200)
#define XBN  8016000         // xb length in shorts
#define BB_OFF 16032000      // byte offset of bt in ws (= XBN*2)
#define KSTRIDE 28672        // shorts per k2-pair step: 2*896*16
#define FRAG1   14336        // shorts per single k2: 896*16
#define IMAG    7168         // shorts: 448*16 (imag fidx offset)

typedef short short8 __attribute__((ext_vector_type(8)));
typedef float float4v __attribute__((ext_vector_type(4)));
typedef float f32x16 __attribute__((ext_vector_type(16)));

#define GU32 const __attribute__((address_space(1))) unsigned int*
#define LU32 __attribute__((address_space(3))) unsigned int*

__device__ inline unsigned short f2bf(float f) {
    union { float f; unsigned u; } v; v.f = f;
    unsigned r = v.u + 0x7FFFu + ((v.u >> 16) & 1u);   // RNE
    return (unsigned short)(r >> 16);
}

// ---- fused prep: blocks 0..349 do basis->bt; blocks 350+ do x->xb ----
__global__ void prep_fused(const float* __restrict__ x,
                           const float* __restrict__ basis,
                           short* __restrict__ xb,
                           short* __restrict__ bt) {
    if (blockIdx.x < 350) {
        // basis (802x800 fp32) -> bt[k2][896][16] bf16 (k-tiled); 89600 chunks
        const int j = blockIdx.x * 256 + threadIdx.x;
        const int k2   = j / 1792;
        const int rem  = j % 1792;
        const int fidx = rem >> 1;
        const int half = rem & 1;
        int src = -1;
        if (fidx < CUT) src = fidx;                                  // real
        else if (fidx >= 448 && fidx < 448 + CUT) src = fidx - 47;   // imag
        short8 o;
        if (src >= 0) {
            const float* p = basis + (size_t)src * 800 + k2 * 16 + half * 8;
            const float4v a = *reinterpret_cast<const float4v*>(p);
            const float4v b = *reinterpret_cast<const float4v*>(p + 4);
            o[0]=f2bf(a[0]); o[1]=f2bf(a[1]); o[2]=f2bf(a[2]); o[3]=f2bf(a[3]);
            o[4]=f2bf(b[0]); o[5]=f2bf(b[1]); o[6]=f2bf(b[2]); o[7]=f2bf(b[3]);
        } else {
            #pragma unroll
            for (int q = 0; q < 8; ++q) o[q] = 0;
        }
        *reinterpret_cast<short8*>(bt + (size_t)j * 8) = o;
    } else {
        // x (fp32) -> xb (bf16, reflect-padded by 400)
        const int n8 = XBN / 8;
        const int nblk = gridDim.x - 350;
        for (int j = (blockIdx.x - 350) * 256 + threadIdx.x; j < n8;
             j += nblk * 256) {
            const int i = j * 8;
            const int s = i - 400;
            short8 o;
            if (s >= 0 && s + 7 < NS) {
                const float4v a = *reinterpret_cast<const float4v*>(x + s);
                const float4v b = *reinterpret_cast<const float4v*>(x + s + 4);
                o[0]=f2bf(a[0]); o[1]=f2bf(a[1]); o[2]=f2bf(a[2]); o[3]=f2bf(a[3]);
                o[4]=f2bf(b[0]); o[5]=f2bf(b[1]); o[6]=f2bf(b[2]); o[7]=f2bf(b[3]);
            } else {
                #pragma unroll
                for (int q = 0; q < 8; ++q) {
                    int sq = s + q;
                    if (sq < 0) sq = -sq;
                    else if (sq >= NS) sq = 2 * NS - 2 - sq;
                    o[q] = f2bf(x[sq]);
                }
            }
            *reinterpret_cast<short8*>(xb + i) = o;
        }
    }
}

#define MF32(A, X, C) C = __builtin_amdgcn_mfma_f32_32x32x16_bf16((A), (X), (C), 0, 0, 0)

// One pipeline step. CA = A(KS) (loaded 2 steps ago), CX = X(KS) (read 1 step
// ago). NA <- A(KS+2) global->reg; NX <- X(KS+1) LDS->reg. No setprio.
#define BODY(KS, CA, CX, NA, NX)                                               \
  {                                                                            \
    if ((KS) <= 22) {                                                          \
      NA[0] = *reinterpret_cast<const short8*>(par + (size_t)((KS)+2)*KSTRIDE);         \
      NA[1] = *reinterpret_cast<const short8*>(par + (size_t)((KS)+2)*KSTRIDE + FRAG1); \
      NA[2] = *reinterpret_cast<const short8*>(pai + (size_t)((KS)+2)*KSTRIDE);         \
      NA[3] = *reinterpret_cast<const short8*>(pai + (size_t)((KS)+2)*KSTRIDE + FRAG1); \
    }                                                                          \
    if ((KS) <= 23) {                                                          \
      NX[0] = *reinterpret_cast<const short8*>(&sX[xoff + 0*6400 + ((KS)+1)*32]);      \
      NX[1] = *reinterpret_cast<const short8*>(&sX[xoff + 0*6400 + ((KS)+1)*32 + 16]); \
      NX[2] = *reinterpret_cast<const short8*>(&sX[xoff + 1*6400 + ((KS)+1)*32]);      \
      NX[3] = *reinterpret_cast<const short8*>(&sX[xoff + 1*6400 + ((KS)+1)*32 + 16]); \
    }                                                                          \
    MF32(CA[0], CX[0], acc_r[0]); MF32(CA[0], CX[2], acc_r[1]);                \
    MF32(CA[2], CX[0], acc_i[0]); MF32(CA[2], CX[2], acc_i[1]);                \
    MF32(CA[1], CX[1], acc_r[0]); MF32(CA[1], CX[3], acc_r[1]);                \
    MF32(CA[3], CX[1], acc_i[0]); MF32(CA[3], CX[3], acc_i[1]);                \
  }

__global__ __launch_bounds__(256, 3)
void stft_mag_kernel(const short* __restrict__ xb,
                     const short* __restrict__ bt,
                     float* __restrict__ out) {
    __shared__ short sX[SLICE_SH];     // 53,248 B — 3 blocks/CU

    const int tid = threadIdx.x;

    // ---- bijective XCD-chunked swizzle (nwg=2191), f-fastest ----
    const int nwg = NTT * 7;
    const int q = nwg >> 3, r = nwg & 7;
    const int bid = blockIdx.x;
    const int xcd = bid & 7, idx = bid >> 3;
    const int wgid = (xcd < r ? xcd * (q + 1) : r * (q + 1) + (xcd - r) * q) + idx;
    const int t0 = (wgid / 7) * TT;
    const int f0 = (wgid % 7) * FT;

    const int lane = tid & 63;
    const int wid  = tid >> 6;
    const int wm   = wid >> 1;       // 0..1 -> which 32 freqs
    const int wn   = wid & 1;        // 0..1 -> which 64 frames
    const int l31  = lane & 31;
    const int lk   = lane >> 5;      // k-half selector

    // ---- A-fragment base pointers into bt[k2][896][16] ----
    const int fb = f0 + wm * 32 + l31;
    const short* par = bt + (size_t)fb * 16 + lk * 8;          // real
    const short* pai = par + IMAG;                             // imag

    short8 A0[4], A1[4], A2[4], XA[4], XB[4];

    // A frags for ks=0,1 issued FIRST so they overlap the sX staging
    A0[0] = *reinterpret_cast<const short8*>(par);
    A0[1] = *reinterpret_cast<const short8*>(par + FRAG1);
    A0[2] = *reinterpret_cast<const short8*>(pai);
    A0[3] = *reinterpret_cast<const short8*>(pai + FRAG1);
    A1[0] = *reinterpret_cast<const short8*>(par + KSTRIDE);
    A1[1] = *reinterpret_cast<const short8*>(par + KSTRIDE + FRAG1);
    A1[2] = *reinterpret_cast<const short8*>(pai + KSTRIDE);
    A1[3] = *reinterpret_cast<const short8*>(pai + KSTRIDE + FRAG1);

    // ---- stage sX: 13 sweeps of global_load_lds width-16, clamped ----
    {
        const int g0 = t0 * HOP + tid * 8;
        short* dst = sX + tid * 8;
        #pragma unroll
        for (int it = 0; it < 13; ++it) {
            int off = g0 + it * 2048;
            if (off > XBN - 8) off = XBN - 8;   // garbage cols masked at store
            __builtin_amdgcn_global_load_lds((GU32)(xb + off),
                                             (LU32)(dst + it * 2048), 16, 0, 0);
        }
    }

    const int xoff = (wn * 64 + l31) * 200 + lk * 8;   // + ni*6400 + ks*32 (+16)

    f32x16 acc_r[2] = {};
    f32x16 acc_i[2] = {};

    // sX landed -> the ONLY barrier (also drains A0/A1 — fine)
    asm volatile("s_waitcnt vmcnt(0)" ::: "memory");
    __builtin_amdgcn_s_barrier();
    asm volatile("" ::: "memory");

    // X frags for ks=0
    XA[0] = *reinterpret_cast<const short8*>(&sX[xoff + 0*6400]);
    XA[1] = *reinterpret_cast<const short8*>(&sX[xoff + 0*6400 + 16]);
    XA[2] = *reinterpret_cast<const short8*>(&sX[xoff + 1*6400]);
    XA[3] = *reinterpret_cast<const short8*>(&sX[xoff + 1*6400 + 16]);

    // ---- barrier-free main pipeline: steps 0..23 (unroll 6 = lcm(3,2)) ----
    #pragma unroll
    for (int jj = 0; jj < 4; ++jj) {
        BODY(6*jj + 0, A0, XA, A2, XB);
        BODY(6*jj + 1, A1, XB, A0, XA);
        BODY(6*jj + 2, A2, XA, A1, XB);
        BODY(6*jj + 3, A0, XB, A2, XA);
        BODY(6*jj + 4, A1, XA, A0, XB);
        BODY(6*jj + 5, A2, XB, A1, XA);
    }
    // step 24: consumes A0 (24%3=0), XA (24%2=0); no prefetch (KS>23)
    BODY(24, A0, XA, A1, XB);

    // ---- epilogue: magnitude + coalesced stores (32 lanes = 32 consecutive t) ----
    #pragma unroll
    for (int ni = 0; ni < 2; ++ni) {
        const int t = t0 + wn * 64 + ni * 32 + l31;
        if (t < NT) {
            #pragma unroll
            for (int reg = 0; reg < 16; ++reg) {
                const int row = (reg & 3) + 8 * (reg >> 2) + 4 * lk;
                const int f = f0 + wm * 32 + row;
                if (f < CUT) {
                    const float vr = acc_r[ni][reg];
                    const float vi = acc_i[ni][reg];
                    out[(size_t)f * NT + t] = sqrtf(vr * vr + vi * vi);
                }
            }
        }
    }
}

extern "C" void kernel_launch(void* const* d_in, const int* in_sizes, int n_in,
                              void* d_out, int out_size, void* d_ws, size_t ws_size,
                              hipStream_t stream) {
    const float* x     = (const float*)d_in[0];
    const float* basis = (const float*)d_in[1];
    float* out = (float*)d_out;

    short* xb = (short*)d_ws;
    short* bt = (short*)((char*)d_ws + BB_OFF);

    prep_fused<<<350 + 2048, 256, 0, stream>>>(x, basis, xb, bt);

    stft_mag_kernel<<<NTT * 7, 256, 0, stream>>>(xb, bt, out);
}